// Round 18
// baseline (2215.970 us; speedup 1.0000x reference)
//
#include <hip/hip_runtime.h>
#include <math.h>

#define NRAYS  16384
#define NSEG   32
#define DIM    128
#define DFF    512
#define ENCD   72
#define PXF    132       // fp32 residual pitch (R3-exact)
#define PH     40        // bf16 per-head pitch (shorts): 80B rows, 16B-aligned
#define HL     (NSEG*PH) // hi->lo short offset inside a head tile
#define SEGL   0.1875f
#define LOOFF  405504    // hi->lo short offset in the weight fragment stream

typedef __attribute__((ext_vector_type(8))) short short8;
typedef __attribute__((ext_vector_type(4))) float f32x4;

__device__ __forceinline__ short f2b(float x) {   // fp32 -> bf16 RNE
    unsigned u = __float_as_uint(x);
    u += 0x7fff + ((u >> 16) & 1);
    return (short)(u >> 16);
}
__device__ __forceinline__ float b2f(short s) {
    return __uint_as_float(((unsigned)(unsigned short)s) << 16);
}
__device__ __forceinline__ void split2(float v, short &h, short &l) {
    h = f2b(v);
    l = f2b(v - b2f(h));
}

// ---------------- weight prep: fp32 -> bf16 hi/lo MFMA B-fragment streams ----------------
__global__ __launch_bounds__(256)
void prep_weights(const float* __restrict__ W_up, const float* __restrict__ Wq,
                  const float* __restrict__ Wk, const float* __restrict__ Wv,
                  const float* __restrict__ Wo, const float* __restrict__ W1,
                  const float* __restrict__ W2, short* __restrict__ out)
{
    int t = blockIdx.x * 256 + threadIdx.x;
    int j    = t & 7;
    int lane = (t >> 3) & 63;
    int krow = ((lane >> 4) << 3) + j;
    int ncol = lane & 15;
    float v;
    if (t < 393216) {
        int f = (t >> 9) & 7;
        int w = (t >> 12) & 3;
        int g = t >> 14;
        int kk = f >> 1, c = f & 1;
        int k = kk * 32 + krow;
        int n = w * 32 + c * 16 + ncol;
        int l = g / 12, gi = g - l * 12;
        if (gi < 4) {
            const float* s4 = (gi == 0) ? Wq : (gi == 1) ? Wk : (gi == 2) ? Wv : Wo;
            v = s4[l * 16384 + k * 128 + n];
        } else if (gi < 8) {
            v = W1[l * 65536 + k * 512 + (gi - 4) * 128 + n];
        } else {
            v = W2[l * 65536 + ((gi - 8) * 128 + k) * 128 + n];
        }
    } else {
        int t2 = t - 393216;         // [0, 12288)
        int w = t2 / 3072;
        int rem = t2 - w * 3072;
        int f = rem >> 9;            // 0..5
        int kk = f >> 1, c = f & 1;
        int k = kk * 32 + krow;
        int n = w * 32 + c * 16 + ncol;
        v = (k < ENCD) ? W_up[k * 128 + n] : 0.0f;
    }
    short h, l2;
    split2(v, h, l2);
    out[t] = h;
    out[t + LOOFF] = l2;
}

// A-operand fragment from swizzled row-major [32][128] bf16 LDS tile
__device__ __forceinline__ short8 lds_afrag(const short* Abuf, int rt, int kk, int lane) {
    int row  = rt * 16 + (lane & 15);
    int byte = row * 256 + kk * 64 + ((lane >> 4) << 4);
    byte ^= (row & 7) << 4;
    return *(const short8*)((const char*)Abuf + byte);
}

#define MFMA(a,b,c) __builtin_amdgcn_mfma_f32_16x16x32_bf16((a),(b),(c),0,0,0)

// OUT(32x128) += A(32xK, hi/lo LDS tiles) @ B(hi/lo frag streams); bf16x3 emulation
template<int NK>
__device__ __forceinline__ void mfma_gemm3(const short* AbH, const short* AbL,
                                           const short* BwH, f32x4 acc[2][2], int lane) {
    const short* BwL = BwH + LOOFF;
#pragma unroll
    for (int kk = 0; kk < NK; ++kk) {
        short8 ah0 = lds_afrag(AbH, 0, kk, lane);
        short8 ah1 = lds_afrag(AbH, 1, kk, lane);
        short8 al0 = lds_afrag(AbL, 0, kk, lane);
        short8 al1 = lds_afrag(AbL, 1, kk, lane);
        short8 bh0 = *(const short8*)(BwH + ((kk * 2 + 0) * 64 + lane) * 8);
        short8 bh1 = *(const short8*)(BwH + ((kk * 2 + 1) * 64 + lane) * 8);
        short8 bl0 = *(const short8*)(BwL + ((kk * 2 + 0) * 64 + lane) * 8);
        short8 bl1 = *(const short8*)(BwL + ((kk * 2 + 1) * 64 + lane) * 8);
        acc[0][0] = MFMA(ah0, bh0, acc[0][0]);
        acc[1][0] = MFMA(ah1, bh0, acc[1][0]);
        acc[0][1] = MFMA(ah0, bh1, acc[0][1]);
        acc[1][1] = MFMA(ah1, bh1, acc[1][1]);
        acc[0][0] = MFMA(al0, bh0, acc[0][0]);
        acc[1][0] = MFMA(al1, bh0, acc[1][0]);
        acc[0][1] = MFMA(al0, bh1, acc[0][1]);
        acc[1][1] = MFMA(al1, bh1, acc[1][1]);
        acc[0][0] = MFMA(ah0, bl0, acc[0][0]);
        acc[1][0] = MFMA(ah1, bl0, acc[1][0]);
        acc[0][1] = MFMA(ah0, bl1, acc[0][1]);
        acc[1][1] = MFMA(ah1, bl1, acc[1][1]);
    }
}

// LayerNorm from fp32 X -> swizzled hi/lo bf16 A-tiles (sync-free: 8-thread shfl reduce)
__device__ __forceinline__ void ln_to_Ab(const float* Xs, const float* sc, const float* bi,
                                         short* AbH, short* AbL, int t) {
    const int s = t >> 3, p = t & 7;
    const float* row = Xs + s * PXF + p * 16;
    float sum = 0.f, sq = 0.f;
#pragma unroll
    for (int j = 0; j < 16; ++j) { float v = row[j]; sum += v; sq = fmaf(v, v, sq); }
#pragma unroll
    for (int off = 1; off < 8; off <<= 1) { sum += __shfl_xor(sum, off); sq += __shfl_xor(sq, off); }
    float mu = sum * 0.0078125f;
    float rs = rsqrtf(sq * 0.0078125f - mu * mu + 1e-5f);
    short8 o0h, o1h, o0l, o1l;
#pragma unroll
    for (int j = 0; j < 8; ++j) {
        float v0 = (row[j]     - mu) * rs * sc[p * 16 + j]     + bi[p * 16 + j];
        float v1 = (row[j + 8] - mu) * rs * sc[p * 16 + 8 + j] + bi[p * 16 + 8 + j];
        short h, l;
        split2(v0, h, l); o0h[j] = h; o0l[j] = l;
        split2(v1, h, l); o1h[j] = h; o1l[j] = l;
    }
    int base = s * 256 + p * 32, swz = (s & 7) << 4;
    *(short8*)((char*)AbH + ((base)      ^ swz)) = o0h;
    *(short8*)((char*)AbH + ((base + 16) ^ swz)) = o1h;
    *(short8*)((char*)AbL + ((base)      ^ swz)) = o0l;
    *(short8*)((char*)AbL + ((base + 16) ^ swz)) = o1l;
}

// 2 rays per 512-thread block (R16 base). FFN: symmetric 2-GEMM regions, 4 barriers:
// {W1c0,W1c1} | bar | {W2c0,W2c1} | bar | {W1c2,W1c3} | bar | {W2c2,W2c3} | bar.
// Regions are pure-write or pure-read on each buffer; X-add order c0..c3 preserved
// per wave -> outputs bit-identical to R17.
__global__ __launch_bounds__(512)
void ray_tf_kernel(const float* __restrict__ points,
                   const float* __restrict__ b_up,
                   const float* __restrict__ ln1_s, const float* __restrict__ ln1_b,
                   const float* __restrict__ ln2_s, const float* __restrict__ ln2_b,
                   const float* __restrict__ b1, const float* __restrict__ b2,
                   const float* __restrict__ w_pool,
                   const float* __restrict__ W_hit, const float* __restrict__ b_hit,
                   const float* __restrict__ W_dc, const float* __restrict__ b_dc,
                   const float* __restrict__ W_dv, const float* __restrict__ b_dv,
                   const short* __restrict__ Wf,
                   float* __restrict__ out)
{
    __shared__ float Xs2[2][NSEG * PXF];
    __shared__ short AbH2[2][NSEG * DIM];
    __shared__ short AbL2[2][NSEG * DIM];
    __shared__ short Qh2[2][4 * 2 * NSEG * PH];   // QP tiles; Fb1 aliases this in FFN
    __shared__ short Kh2[2][4 * 2 * NSEG * PH];   // K tiles;  Fb0 aliases this in FFN
    __shared__ float LG2[2][NSEG], SCC2[2][NSEG], SCV2[2][NSEG], POOL2[2][DIM];

    const int sub  = threadIdx.x >> 8;
    const int t    = threadIdx.x & 255;
    const int lane = t & 63;
    const int w    = t >> 6;
    const int ray  = blockIdx.x * 2 + sub;

    float* X    = Xs2[sub];
    short* AbH  = AbH2[sub];
    short* AbL  = AbL2[sub];
    short* Qh   = Qh2[sub] + w * (2 * NSEG * PH);
    short* Kh   = Kh2[sub] + w * (2 * NSEG * PH);
    short* Fb0H = Kh2[sub];            // FFN buffer 0 (K tiles dead after QK^T)
    short* Fb0L = Kh2[sub] + 4096;
    short* Fb1H = Qh2[sub];            // FFN buffer 1 (Q/P tiles dead after PV)
    short* Fb1L = Qh2[sub] + 4096;
    float* LG   = LG2[sub];
    float* SCC  = SCC2[sub];
    float* SCV  = SCV2[sub];
    float* POOL = POOL2[sub];

    // ---- ray geometry (sub-block-uniform) ----
    const float ox = points[ray*6+0], oy = points[ray*6+1], oz = points[ray*6+2];
    float dx = points[ray*6+3] - ox, dy = points[ray*6+4] - oy, dz = points[ray*6+5] - oz;
    const float dn = sqrtf(dx*dx + dy*dy + dz*dz);
    dx /= dn; dy /= dn; dz /= dn;
    const float bq = ox*dx + oy*dy + oz*dz;
    const float cq = ox*ox + oy*oy + oz*oz - 9.0f;
    const float sqv = sqrtf(fmaxf(bq*bq - cq, 0.0f));
    const float t1 = -bq - sqv, t2 = -bq + sqv;
    int n_left = 0;
#pragma unroll
    for (int j = 0; j < NSEG; ++j) {
        float tj = t1 + (float)j * SEGL;
        n_left += (tj < t2) ? 1 : 0;
    }

    // ---- positional encoding -> AbH/AbL (swizzled; cols 72..95 zero for K-pad) ----
    for (int e = t; e < NSEG * 96; e += 256) {
        int s = e / 96, c = e - (e / 96) * 96;
        float val = 0.f;
        if (c < ENCD) {
            int ep = c / 36, rem = c - ep * 36, coord = rem / 12, u = rem - coord * 12;
            int jj = s + ep;
            float tj = t1 + (float)jj * SEGL;
            float oc = (coord == 0) ? ox : ((coord == 1) ? oy : oz);
            float vc = (coord == 0) ? dx : ((coord == 1) ? dy : dz);
            float pv = (oc + vc * tj) / 3.0f;
            if (s >= n_left) pv = 0.0f;
            int fq = (u < 6) ? u : (u - 6);
            float ang = pv * (3.14159265358979323846f * (float)(1 << fq));
            val = (u < 6) ? __sinf(ang) : __cosf(ang);
        }
        int byte = (s * 256 + c * 2) ^ ((s & 7) << 4);
        short h, l;
        split2(val, h, l);
        *(short*)((char*)AbH + byte) = h;
        *(short*)((char*)AbL + byte) = l;
    }
    __syncthreads();

    // ---- x = enc @ W_up + b_up ----
    {
        f32x4 acc[2][2] = {};
        mfma_gemm3<3>(AbH, AbL, Wf + 393216 + w * 3072, acc, lane);
#pragma unroll
        for (int c = 0; c < 2; ++c) {
            int colg = w * 32 + c * 16 + (lane & 15);
            float bv = b_up[colg];
#pragma unroll
            for (int rt = 0; rt < 2; ++rt)
#pragma unroll
                for (int i = 0; i < 4; ++i) {
                    int row = rt * 16 + ((lane >> 4) << 2) + i;
                    X[row * PXF + colg] = acc[rt][c][i] + bv;
                }
        }
    }
    __syncthreads();

    const float scale = 0.17677669529663687f;  // 1/sqrt(32)

    for (int l = 0; l < 2; ++l) {
        const short* WL = Wf + l * 196608;
        // LN1 -> Ab
        ln_to_Ab(X, ln1_s + l * DIM, ln1_b + l * DIM, AbH, AbL, t);
        __syncthreads();

        // Q gemm -> write Q tile immediately (acc dies right away)
        {
            f32x4 aq[2][2] = {};
            mfma_gemm3<4>(AbH, AbL, WL + 0 * 16384 + w * 4096, aq, lane);
#pragma unroll
            for (int c = 0; c < 2; ++c)
#pragma unroll
                for (int rt = 0; rt < 2; ++rt)
#pragma unroll
                    for (int i = 0; i < 4; ++i) {
                        int row = rt * 16 + ((lane >> 4) << 2) + i;
                        int cl  = c * 16 + (lane & 15);
                        short h, lo;
                        split2(aq[rt][c][i], h, lo);
                        Qh[row * PH + cl] = h; Qh[HL + row * PH + cl] = lo;
                    }
        }
        // K gemm -> write K tile immediately
        {
            f32x4 ak[2][2] = {};
            mfma_gemm3<4>(AbH, AbL, WL + 1 * 16384 + w * 4096, ak, lane);
#pragma unroll
            for (int c = 0; c < 2; ++c)
#pragma unroll
                for (int rt = 0; rt < 2; ++rt)
#pragma unroll
                    for (int i = 0; i < 4; ++i) {
                        int row = rt * 16 + ((lane >> 4) << 2) + i;
                        int cl  = c * 16 + (lane & 15);
                        short h, lo;
                        split2(ak[rt][c][i], h, lo);
                        Kh[row * PH + cl] = h; Kh[HL + row * PH + cl] = lo;
                    }
        }
        // V gemm -> transpose to PV B-fragments immediately (av dies here)
        short8 vbh[2], vbl[2];
        {
            f32x4 av[2][2] = {};
            mfma_gemm3<4>(AbH, AbL, WL + 2 * 16384 + w * 4096, av, lane);
            // Shuffle BOTH rt candidates; select by DESTINATION half. Value-exact.
#pragma unroll
            for (int ct = 0; ct < 2; ++ct)
#pragma unroll
                for (int j = 0; j < 8; ++j) {
                    int srcl = ((((lane >> 4) & 1) * 2 + (j >> 2)) << 4) | (lane & 15);
                    float v0 = __shfl(av[0][ct][j & 3], srcl);
                    float v1 = __shfl(av[1][ct][j & 3], srcl);
                    float vv = (lane < 32) ? v0 : v1;
                    short h, lo;
                    split2(vv, h, lo);
                    vbh[ct][j] = h; vbl[ct][j] = lo;
                }
        }

        // ---- attention (one head per wave, bf16x3; R3 op order) ----
        {
            f32x4 sA[2][2] = {};
            {
                short8 qh[2], ql[2], kh[2], kl[2];
#pragma unroll
                for (int rt = 0; rt < 2; ++rt) {
                    int byte = (rt * 16 + (lane & 15)) * (PH * 2) + ((lane >> 4) << 4);
                    qh[rt] = *(const short8*)((const char*)Qh + byte);
                    ql[rt] = *(const short8*)((const char*)Qh + HL * 2 + byte);
                }
#pragma unroll
                for (int ct = 0; ct < 2; ++ct) {
                    int byte = (ct * 16 + (lane & 15)) * (PH * 2) + ((lane >> 4) << 4);
                    kh[ct] = *(const short8*)((const char*)Kh + byte);
                    kl[ct] = *(const short8*)((const char*)Kh + HL * 2 + byte);
                }
#pragma unroll
                for (int ct = 0; ct < 2; ++ct)
#pragma unroll
                    for (int rt = 0; rt < 2; ++rt) {
                        sA[rt][ct] = MFMA(qh[rt], kh[ct], sA[rt][ct]);
                        sA[rt][ct] = MFMA(ql[rt], kh[ct], sA[rt][ct]);
                        sA[rt][ct] = MFMA(qh[rt], kl[ct], sA[rt][ct]);
                    }
            }

            // row softmax -> P into QP tile (hi/lo); in-wave DS ordering (R3 construct)
#pragma unroll
            for (int rt = 0; rt < 2; ++rt)
#pragma unroll
                for (int i = 0; i < 4; ++i) {
                    float v0 = sA[rt][0][i] * scale, v1 = sA[rt][1][i] * scale;
                    float mx = fmaxf(v0, v1);
                    mx = fmaxf(mx, __shfl_xor(mx, 1));
                    mx = fmaxf(mx, __shfl_xor(mx, 2));
                    mx = fmaxf(mx, __shfl_xor(mx, 4));
                    mx = fmaxf(mx, __shfl_xor(mx, 8));
                    float e0 = __expf(v0 - mx), e1 = __expf(v1 - mx);
                    float sm = e0 + e1;
                    sm += __shfl_xor(sm, 1);
                    sm += __shfl_xor(sm, 2);
                    sm += __shfl_xor(sm, 4);
                    sm += __shfl_xor(sm, 8);
                    float inv = 1.0f / sm;
                    int row = rt * 16 + ((lane >> 4) << 2) + i;
                    short h, lo;
                    split2(e0 * inv, h, lo);
                    Qh[row * PH + (lane & 15)] = h;
                    Qh[HL + row * PH + (lane & 15)] = lo;
                    split2(e1 * inv, h, lo);
                    Qh[row * PH + 16 + (lane & 15)] = h;
                    Qh[HL + row * PH + 16 + (lane & 15)] = lo;
                }

            // O = P @ V  (P from QP tile, V from registers)
            f32x4 oA[2][2] = {};
            {
                short8 ph[2], pl[2];
#pragma unroll
                for (int rt = 0; rt < 2; ++rt) {
                    int byte = (rt * 16 + (lane & 15)) * (PH * 2) + ((lane >> 4) << 4);
                    ph[rt] = *(const short8*)((const char*)Qh + byte);
                    pl[rt] = *(const short8*)((const char*)Qh + HL * 2 + byte);
                }
#pragma unroll
                for (int ct = 0; ct < 2; ++ct)
#pragma unroll
                    for (int rt = 0; rt < 2; ++rt) {
                        oA[rt][ct] = MFMA(ph[rt], vbh[ct], oA[rt][ct]);
                        oA[rt][ct] = MFMA(pl[rt], vbh[ct], oA[rt][ct]);
                        oA[rt][ct] = MFMA(ph[rt], vbl[ct], oA[rt][ct]);
                    }
            }

            // barrier HERE: all waves' QKV reads of Ab complete before O overwrites it
            __syncthreads();

            // O -> Ab (hi/lo swizzled); head w owns cols [32w,32w+32)
#pragma unroll
            for (int rt = 0; rt < 2; ++rt)
#pragma unroll
                for (int ct = 0; ct < 2; ++ct)
#pragma unroll
                    for (int i = 0; i < 4; ++i) {
                        int row  = rt * 16 + ((lane >> 4) << 2) + i;
                        int colg = w * 32 + ct * 16 + (lane & 15);
                        int byte = (row * 256 + colg * 2) ^ ((row & 7) << 4);
                        short h, lo;
                        split2(oA[rt][ct][i], h, lo);
                        *(short*)((char*)AbH + byte) = h;
                        *(short*)((char*)AbL + byte) = lo;
                    }
        }
        __syncthreads();

        // x += O @ Wo
        {
            f32x4 ac[2][2] = {};
            mfma_gemm3<4>(AbH, AbL, WL + 3 * 16384 + w * 4096, ac, lane);
#pragma unroll
            for (int c = 0; c < 2; ++c) {
                int colg = w * 32 + c * 16 + (lane & 15);
#pragma unroll
                for (int rt = 0; rt < 2; ++rt)
#pragma unroll
                    for (int i = 0; i < 4; ++i) {
                        int row = rt * 16 + ((lane >> 4) << 2) + i;
                        X[row * PXF + colg] += ac[rt][c][i];
                    }
            }
        }
        __syncthreads();

        // LN2 -> Ab
        ln_to_Ab(X, ln2_s + l * DIM, ln2_b + l * DIM, AbH, AbL, t);
        __syncthreads();

        // FFN: symmetric 2-GEMM regions, 4 barriers.
#define FFN_W1(c4, FH, FL) do { \
    f32x4 f1[2][2] = {}; \
    mfma_gemm3<4>(AbH, AbL, WL + (4 + (c4)) * 16384 + w * 4096, f1, lane); \
    _Pragma("unroll") \
    for (int c = 0; c < 2; ++c) { \
        int colg = w * 32 + c * 16 + (lane & 15); \
        float bv = b1[l * DFF + (c4) * 128 + colg]; \
        _Pragma("unroll") \
        for (int rt = 0; rt < 2; ++rt) \
            _Pragma("unroll") \
            for (int i = 0; i < 4; ++i) { \
                int row  = rt * 16 + ((lane >> 4) << 2) + i; \
                float v  = fmaxf(f1[rt][c][i] + bv, 0.0f); \
                int byte = (row * 256 + colg * 2) ^ ((row & 7) << 4); \
                short h, lo; \
                split2(v, h, lo); \
                *(short*)((char*)(FH) + byte) = h; \
                *(short*)((char*)(FL) + byte) = lo; \
            } \
    } \
} while (0)

#define FFN_W2(c4, FH, FL) do { \
    f32x4 f2a[2][2] = {}; \
    mfma_gemm3<4>((FH), (FL), WL + (8 + (c4)) * 16384 + w * 4096, f2a, lane); \
    _Pragma("unroll") \
    for (int c = 0; c < 2; ++c) { \
        int colg = w * 32 + c * 16 + (lane & 15); \
        float bv = ((c4) == 0) ? b2[l * DIM + colg] : 0.0f; \
        _Pragma("unroll") \
        for (int rt = 0; rt < 2; ++rt) \
            _Pragma("unroll") \
            for (int i = 0; i < 4; ++i) { \
                int row = rt * 16 + ((lane >> 4) << 2) + i; \
                X[row * PXF + colg] += f2a[rt][c][i] + bv; \
            } \
    } \
} while (0)

        FFN_W1(0, Fb0H, Fb0L);
        FFN_W1(1, Fb1H, Fb1L);
        __syncthreads();
        FFN_W2(0, Fb0H, Fb0L);
        FFN_W2(1, Fb1H, Fb1L);
        __syncthreads();
        FFN_W1(2, Fb0H, Fb0L);
        FFN_W1(3, Fb1H, Fb1L);
        __syncthreads();
        FFN_W2(2, Fb0H, Fb0L);
        FFN_W2(3, Fb1H, Fb1L);
        __syncthreads();
#undef FFN_W1
#undef FFN_W2
    }

    // ---- pooling logits ----
    {
        const int s = t >> 3, p = t & 7;
        float acc = 0.f;
        const float* row = X + s * PXF + p * 16;
        const float* wp = w_pool + p * 16;
#pragma unroll
        for (int j = 0; j < 16; ++j) acc = fmaf(row[j], wp[j], acc);
#pragma unroll
        for (int off = 1; off < 8; off <<= 1) acc += __shfl_xor(acc, off);
        if (p == 0) LG[s] = acc;
    }
    __syncthreads();
    if (t < DIM) {
        float m = -1e30f;
        for (int s = 0; s < NSEG; ++s) m = fmaxf(m, LG[s]);
        float ssum = 0.f;
        for (int s = 0; s < NSEG; ++s) ssum += __expf(LG[s] - m);
        float inv = 1.0f / ssum;
        float acc = 0.f;
        for (int s = 0; s < NSEG; ++s) acc = fmaf(__expf(LG[s] - m), X[s * PXF + t], acc);
        POOL[t] = acc * inv;
    }
    {
        const int s = t >> 3, p = t & 7;
        float c = 0.f, v = 0.f;
        const float* row = X + s * PXF + p * 16;
#pragma unroll
        for (int j = 0; j < 16; ++j) {
            float x = row[j];
            c = fmaf(x, W_dc[p * 16 + j], c);
            v = fmaf(x, W_dv[p * 16 + j], v);
        }
#pragma unroll
        for (int off = 1; off < 8; off <<= 1) { c += __shfl_xor(c, off); v += __shfl_xor(v, off); }
        if (p == 0) {
            SCC[s] = c + b_dc[0];
            SCV[s] = fminf(fmaxf(v + b_dv[0], 0.0f), 1.0f);
        }
    }
    __syncthreads();
    if (t < 64) {
        float v = POOL[t] * W_hit[t] + POOL[t + 64] * W_hit[t + 64];
#pragma unroll
        for (int off = 1; off < 64; off <<= 1) v += __shfl_xor(v, off);
        if (t == 0) {
            float hv = v + b_hit[0];
            out[ray] = (n_left == 0) ? -100.0f : hv;
        }
    }
    if (t == 255) {
        float best = -1e30f; int am = 0;
        for (int s = 0; s < NSEG; ++s) {
            if (s < n_left) {
                float cv = SCC[s];
                if (cv > best) { best = cv; am = s; }
            }
        }
        out[NRAYS + ray] = SCV[am] + (float)am * SEGL + t1;
    }
}

extern "C" void kernel_launch(void* const* d_in, const int* in_sizes, int n_in,
                              void* d_out, int out_size, void* d_ws, size_t ws_size,
                              hipStream_t stream) {
    (void)in_sizes; (void)n_in; (void)ws_size; (void)out_size;
    const float* points = (const float*)d_in[0];
    const float* W_up   = (const float*)d_in[1];
    const float* b_up   = (const float*)d_in[2];
    const float* ln1_s  = (const float*)d_in[3];
    const float* ln1_b  = (const float*)d_in[4];
    const float* Wq     = (const float*)d_in[5];
    const float* Wk     = (const float*)d_in[6];
    const float* Wv     = (const float*)d_in[7];
    const float* Wo     = (const float*)d_in[8];
    const float* ln2_s  = (const float*)d_in[9];
    const float* ln2_b  = (const float*)d_in[10];
    const float* W1     = (const float*)d_in[11];
    const float* b1     = (const float*)d_in[12];
    const float* W2     = (const float*)d_in[13];
    const float* b2     = (const float*)d_in[14];
    const float* w_pool = (const float*)d_in[15];
    const float* W_hit  = (const float*)d_in[16];
    const float* b_hit  = (const float*)d_in[17];
    const float* W_dc   = (const float*)d_in[18];
    const float* b_dc   = (const float*)d_in[19];
    const float* W_dv   = (const float*)d_in[20];
    const float* b_dv   = (const float*)d_in[21];
    short* Wf = (short*)d_ws;
    float* out = (float*)d_out;

    hipLaunchKernelGGL(prep_weights, dim3(1584), dim3(256), 0, stream,
                       W_up, Wq, Wk, Wv, Wo, W1, W2, Wf);
    hipLaunchKernelGGL(ray_tf_kernel, dim3(NRAYS / 2), dim3(512), 0, stream,
                       points, b_up, ln1_s, ln1_b, ln2_s, ln2_b, b1, b2, w_pool,
                       W_hit, b_hit, W_dc, b_dc, W_dv, b_dv, Wf, out);
}

// Round 19
// 1893.092 us; speedup vs baseline: 1.1706x; 1.1706x over previous
//
#include <hip/hip_runtime.h>
#include <math.h>

#define NRAYS  16384
#define NSEG   32
#define DIM    128
#define DFF    512
#define ENCD   72
#define PXF    132       // fp32 residual pitch (R3-exact)
#define PH     40        // bf16 per-head pitch (shorts): 80B rows, 16B-aligned
#define HL     (NSEG*PH) // hi->lo short offset inside a head tile
#define SEGL   0.1875f
#define LOOFF  405504    // hi->lo short offset in the weight fragment stream

typedef __attribute__((ext_vector_type(8))) short short8;
typedef __attribute__((ext_vector_type(4))) float f32x4;

__device__ __forceinline__ short f2b(float x) {   // fp32 -> bf16 RNE
    unsigned u = __float_as_uint(x);
    u += 0x7fff + ((u >> 16) & 1);
    return (short)(u >> 16);
}
__device__ __forceinline__ float b2f(short s) {
    return __uint_as_float(((unsigned)(unsigned short)s) << 16);
}
__device__ __forceinline__ void split2(float v, short &h, short &l) {
    h = f2b(v);
    l = f2b(v - b2f(h));
}

// ---------------- weight prep: fp32 -> bf16 hi/lo MFMA B-fragment streams ----------------
__global__ __launch_bounds__(256)
void prep_weights(const float* __restrict__ W_up, const float* __restrict__ Wq,
                  const float* __restrict__ Wk, const float* __restrict__ Wv,
                  const float* __restrict__ Wo, const float* __restrict__ W1,
                  const float* __restrict__ W2, short* __restrict__ out)
{
    int t = blockIdx.x * 256 + threadIdx.x;
    int j    = t & 7;
    int lane = (t >> 3) & 63;
    int krow = ((lane >> 4) << 3) + j;
    int ncol = lane & 15;
    float v;
    if (t < 393216) {
        int f = (t >> 9) & 7;
        int w = (t >> 12) & 3;
        int g = t >> 14;
        int kk = f >> 1, c = f & 1;
        int k = kk * 32 + krow;
        int n = w * 32 + c * 16 + ncol;
        int l = g / 12, gi = g - l * 12;
        if (gi < 4) {
            const float* s4 = (gi == 0) ? Wq : (gi == 1) ? Wk : (gi == 2) ? Wv : Wo;
            v = s4[l * 16384 + k * 128 + n];
        } else if (gi < 8) {
            v = W1[l * 65536 + k * 512 + (gi - 4) * 128 + n];
        } else {
            v = W2[l * 65536 + ((gi - 8) * 128 + k) * 128 + n];
        }
    } else {
        int t2 = t - 393216;         // [0, 12288)
        int w = t2 / 3072;
        int rem = t2 - w * 3072;
        int f = rem >> 9;            // 0..5
        int kk = f >> 1, c = f & 1;
        int k = kk * 32 + krow;
        int n = w * 32 + c * 16 + ncol;
        v = (k < ENCD) ? W_up[k * 128 + n] : 0.0f;
    }
    short h, l2;
    split2(v, h, l2);
    out[t] = h;
    out[t + LOOFF] = l2;
}

// A-operand fragment from swizzled row-major [32][128] bf16 LDS tile
__device__ __forceinline__ short8 lds_afrag(const short* Abuf, int rt, int kk, int lane) {
    int row  = rt * 16 + (lane & 15);
    int byte = row * 256 + kk * 64 + ((lane >> 4) << 4);
    byte ^= (row & 7) << 4;
    return *(const short8*)((const char*)Abuf + byte);
}

#define MFMA(a,b,c) __builtin_amdgcn_mfma_f32_16x16x32_bf16((a),(b),(c),0,0,0)

// OUT(32x128) += A(32xK, hi/lo LDS tiles) @ B(hi/lo frag streams); bf16x3 emulation
template<int NK>
__device__ __forceinline__ void mfma_gemm3(const short* AbH, const short* AbL,
                                           const short* BwH, f32x4 acc[2][2], int lane) {
    const short* BwL = BwH + LOOFF;
#pragma unroll
    for (int kk = 0; kk < NK; ++kk) {
        short8 ah0 = lds_afrag(AbH, 0, kk, lane);
        short8 ah1 = lds_afrag(AbH, 1, kk, lane);
        short8 al0 = lds_afrag(AbL, 0, kk, lane);
        short8 al1 = lds_afrag(AbL, 1, kk, lane);
        short8 bh0 = *(const short8*)(BwH + ((kk * 2 + 0) * 64 + lane) * 8);
        short8 bh1 = *(const short8*)(BwH + ((kk * 2 + 1) * 64 + lane) * 8);
        short8 bl0 = *(const short8*)(BwL + ((kk * 2 + 0) * 64 + lane) * 8);
        short8 bl1 = *(const short8*)(BwL + ((kk * 2 + 1) * 64 + lane) * 8);
        acc[0][0] = MFMA(ah0, bh0, acc[0][0]);
        acc[1][0] = MFMA(ah1, bh0, acc[1][0]);
        acc[0][1] = MFMA(ah0, bh1, acc[0][1]);
        acc[1][1] = MFMA(ah1, bh1, acc[1][1]);
        acc[0][0] = MFMA(al0, bh0, acc[0][0]);
        acc[1][0] = MFMA(al1, bh0, acc[1][0]);
        acc[0][1] = MFMA(al0, bh1, acc[0][1]);
        acc[1][1] = MFMA(al1, bh1, acc[1][1]);
        acc[0][0] = MFMA(ah0, bl0, acc[0][0]);
        acc[1][0] = MFMA(ah1, bl0, acc[1][0]);
        acc[0][1] = MFMA(ah0, bl1, acc[0][1]);
        acc[1][1] = MFMA(ah1, bl1, acc[1][1]);
    }
}

// LayerNorm from fp32 X -> swizzled hi/lo bf16 A-tiles (sync-free: 8-thread shfl reduce)
__device__ __forceinline__ void ln_to_Ab(const float* Xs, const float* sc, const float* bi,
                                         short* AbH, short* AbL, int t) {
    const int s = t >> 3, p = t & 7;
    const float* row = Xs + s * PXF + p * 16;
    float sum = 0.f, sq = 0.f;
#pragma unroll
    for (int j = 0; j < 16; ++j) { float v = row[j]; sum += v; sq = fmaf(v, v, sq); }
#pragma unroll
    for (int off = 1; off < 8; off <<= 1) { sum += __shfl_xor(sum, off); sq += __shfl_xor(sq, off); }
    float mu = sum * 0.0078125f;
    float rs = rsqrtf(sq * 0.0078125f - mu * mu + 1e-5f);
    short8 o0h, o1h, o0l, o1l;
#pragma unroll
    for (int j = 0; j < 8; ++j) {
        float v0 = (row[j]     - mu) * rs * sc[p * 16 + j]     + bi[p * 16 + j];
        float v1 = (row[j + 8] - mu) * rs * sc[p * 16 + 8 + j] + bi[p * 16 + 8 + j];
        short h, l;
        split2(v0, h, l); o0h[j] = h; o0l[j] = l;
        split2(v1, h, l); o1h[j] = h; o1l[j] = l;
    }
    int base = s * 256 + p * 32, swz = (s & 7) << 4;
    *(short8*)((char*)AbH + ((base)      ^ swz)) = o0h;
    *(short8*)((char*)AbH + ((base + 16) ^ swz)) = o1h;
    *(short8*)((char*)AbL + ((base)      ^ swz)) = o0l;
    *(short8*)((char*)AbL + ((base + 16) ^ swz)) = o1l;
}

// 2 rays per 512-thread block (R16 structure), plus FFN double-buffered Fb:
// Fb0 aliases K tiles (dead after QK^T), Fb1 aliases Q/P tiles (dead after PV).
// 5 barriers per FFN; each region holds ONE GEMM chain (W2ck serialized with W1ck+1
// via Fb dependence) -> stays under the 128-VGPR cap without spills (R18 lesson:
// two independent GEMMs per region overflow the cap).
__global__ __launch_bounds__(512)
void ray_tf_kernel(const float* __restrict__ points,
                   const float* __restrict__ b_up,
                   const float* __restrict__ ln1_s, const float* __restrict__ ln1_b,
                   const float* __restrict__ ln2_s, const float* __restrict__ ln2_b,
                   const float* __restrict__ b1, const float* __restrict__ b2,
                   const float* __restrict__ w_pool,
                   const float* __restrict__ W_hit, const float* __restrict__ b_hit,
                   const float* __restrict__ W_dc, const float* __restrict__ b_dc,
                   const float* __restrict__ W_dv, const float* __restrict__ b_dv,
                   const short* __restrict__ Wf,
                   float* __restrict__ out)
{
    __shared__ float Xs2[2][NSEG * PXF];
    __shared__ short AbH2[2][NSEG * DIM];
    __shared__ short AbL2[2][NSEG * DIM];
    __shared__ short Qh2[2][4 * 2 * NSEG * PH];   // QP tiles; Fb1 aliases this in FFN
    __shared__ short Kh2[2][4 * 2 * NSEG * PH];   // K tiles;  Fb0 aliases this in FFN
    __shared__ float LG2[2][NSEG], SCC2[2][NSEG], SCV2[2][NSEG], POOL2[2][DIM];

    const int sub  = threadIdx.x >> 8;
    const int t    = threadIdx.x & 255;
    const int lane = t & 63;
    const int w    = t >> 6;
    const int ray  = blockIdx.x * 2 + sub;

    float* X    = Xs2[sub];
    short* AbH  = AbH2[sub];
    short* AbL  = AbL2[sub];
    short* Qh   = Qh2[sub] + w * (2 * NSEG * PH);
    short* Kh   = Kh2[sub] + w * (2 * NSEG * PH);
    short* Fb0H = Kh2[sub];            // FFN buffer 0 (K tiles dead after QK^T)
    short* Fb0L = Kh2[sub] + 4096;
    short* Fb1H = Qh2[sub];            // FFN buffer 1 (Q/P tiles dead after PV)
    short* Fb1L = Qh2[sub] + 4096;
    float* LG   = LG2[sub];
    float* SCC  = SCC2[sub];
    float* SCV  = SCV2[sub];
    float* POOL = POOL2[sub];

    // ---- ray geometry (sub-block-uniform) ----
    const float ox = points[ray*6+0], oy = points[ray*6+1], oz = points[ray*6+2];
    float dx = points[ray*6+3] - ox, dy = points[ray*6+4] - oy, dz = points[ray*6+5] - oz;
    const float dn = sqrtf(dx*dx + dy*dy + dz*dz);
    dx /= dn; dy /= dn; dz /= dn;
    const float bq = ox*dx + oy*dy + oz*dz;
    const float cq = ox*ox + oy*oy + oz*oz - 9.0f;
    const float sqv = sqrtf(fmaxf(bq*bq - cq, 0.0f));
    const float t1 = -bq - sqv, t2 = -bq + sqv;
    int n_left = 0;
#pragma unroll
    for (int j = 0; j < NSEG; ++j) {
        float tj = t1 + (float)j * SEGL;
        n_left += (tj < t2) ? 1 : 0;
    }

    // ---- positional encoding -> AbH/AbL (swizzled; cols 72..95 zero for K-pad) ----
    for (int e = t; e < NSEG * 96; e += 256) {
        int s = e / 96, c = e - (e / 96) * 96;
        float val = 0.f;
        if (c < ENCD) {
            int ep = c / 36, rem = c - ep * 36, coord = rem / 12, u = rem - coord * 12;
            int jj = s + ep;
            float tj = t1 + (float)jj * SEGL;
            float oc = (coord == 0) ? ox : ((coord == 1) ? oy : oz);
            float vc = (coord == 0) ? dx : ((coord == 1) ? dy : dz);
            float pv = (oc + vc * tj) / 3.0f;
            if (s >= n_left) pv = 0.0f;
            int fq = (u < 6) ? u : (u - 6);
            float ang = pv * (3.14159265358979323846f * (float)(1 << fq));
            val = (u < 6) ? __sinf(ang) : __cosf(ang);
        }
        int byte = (s * 256 + c * 2) ^ ((s & 7) << 4);
        short h, l;
        split2(val, h, l);
        *(short*)((char*)AbH + byte) = h;
        *(short*)((char*)AbL + byte) = l;
    }
    __syncthreads();

    // ---- x = enc @ W_up + b_up ----
    {
        f32x4 acc[2][2] = {};
        mfma_gemm3<3>(AbH, AbL, Wf + 393216 + w * 3072, acc, lane);
#pragma unroll
        for (int c = 0; c < 2; ++c) {
            int colg = w * 32 + c * 16 + (lane & 15);
            float bv = b_up[colg];
#pragma unroll
            for (int rt = 0; rt < 2; ++rt)
#pragma unroll
                for (int i = 0; i < 4; ++i) {
                    int row = rt * 16 + ((lane >> 4) << 2) + i;
                    X[row * PXF + colg] = acc[rt][c][i] + bv;
                }
        }
    }
    __syncthreads();

    const float scale = 0.17677669529663687f;  // 1/sqrt(32)

    for (int l = 0; l < 2; ++l) {
        const short* WL = Wf + l * 196608;
        // LN1 -> Ab
        ln_to_Ab(X, ln1_s + l * DIM, ln1_b + l * DIM, AbH, AbL, t);
        __syncthreads();

        // Q gemm -> write Q tile immediately (acc dies right away)
        {
            f32x4 aq[2][2] = {};
            mfma_gemm3<4>(AbH, AbL, WL + 0 * 16384 + w * 4096, aq, lane);
#pragma unroll
            for (int c = 0; c < 2; ++c)
#pragma unroll
                for (int rt = 0; rt < 2; ++rt)
#pragma unroll
                    for (int i = 0; i < 4; ++i) {
                        int row = rt * 16 + ((lane >> 4) << 2) + i;
                        int cl  = c * 16 + (lane & 15);
                        short h, lo;
                        split2(aq[rt][c][i], h, lo);
                        Qh[row * PH + cl] = h; Qh[HL + row * PH + cl] = lo;
                    }
        }
        // K gemm -> write K tile immediately
        {
            f32x4 ak[2][2] = {};
            mfma_gemm3<4>(AbH, AbL, WL + 1 * 16384 + w * 4096, ak, lane);
#pragma unroll
            for (int c = 0; c < 2; ++c)
#pragma unroll
                for (int rt = 0; rt < 2; ++rt)
#pragma unroll
                    for (int i = 0; i < 4; ++i) {
                        int row = rt * 16 + ((lane >> 4) << 2) + i;
                        int cl  = c * 16 + (lane & 15);
                        short h, lo;
                        split2(ak[rt][c][i], h, lo);
                        Kh[row * PH + cl] = h; Kh[HL + row * PH + cl] = lo;
                    }
        }
        // V gemm -> transpose to PV B-fragments immediately (av dies here)
        short8 vbh[2], vbl[2];
        {
            f32x4 av[2][2] = {};
            mfma_gemm3<4>(AbH, AbL, WL + 2 * 16384 + w * 4096, av, lane);
            // Shuffle BOTH rt candidates; select by DESTINATION half. Value-exact.
#pragma unroll
            for (int ct = 0; ct < 2; ++ct)
#pragma unroll
                for (int j = 0; j < 8; ++j) {
                    int srcl = ((((lane >> 4) & 1) * 2 + (j >> 2)) << 4) | (lane & 15);
                    float v0 = __shfl(av[0][ct][j & 3], srcl);
                    float v1 = __shfl(av[1][ct][j & 3], srcl);
                    float vv = (lane < 32) ? v0 : v1;
                    short h, lo;
                    split2(vv, h, lo);
                    vbh[ct][j] = h; vbl[ct][j] = lo;
                }
        }

        // ---- attention (one head per wave, bf16x3; R3 op order) ----
        {
            f32x4 sA[2][2] = {};
            {
                short8 qh[2], ql[2], kh[2], kl[2];
#pragma unroll
                for (int rt = 0; rt < 2; ++rt) {
                    int byte = (rt * 16 + (lane & 15)) * (PH * 2) + ((lane >> 4) << 4);
                    qh[rt] = *(const short8*)((const char*)Qh + byte);
                    ql[rt] = *(const short8*)((const char*)Qh + HL * 2 + byte);
                }
#pragma unroll
                for (int ct = 0; ct < 2; ++ct) {
                    int byte = (ct * 16 + (lane & 15)) * (PH * 2) + ((lane >> 4) << 4);
                    kh[ct] = *(const short8*)((const char*)Kh + byte);
                    kl[ct] = *(const short8*)((const char*)Kh + HL * 2 + byte);
                }
#pragma unroll
                for (int ct = 0; ct < 2; ++ct)
#pragma unroll
                    for (int rt = 0; rt < 2; ++rt) {
                        sA[rt][ct] = MFMA(qh[rt], kh[ct], sA[rt][ct]);
                        sA[rt][ct] = MFMA(ql[rt], kh[ct], sA[rt][ct]);
                        sA[rt][ct] = MFMA(qh[rt], kl[ct], sA[rt][ct]);
                    }
            }

            // row softmax -> P into QP tile (hi/lo); in-wave DS ordering (R3 construct)
#pragma unroll
            for (int rt = 0; rt < 2; ++rt)
#pragma unroll
                for (int i = 0; i < 4; ++i) {
                    float v0 = sA[rt][0][i] * scale, v1 = sA[rt][1][i] * scale;
                    float mx = fmaxf(v0, v1);
                    mx = fmaxf(mx, __shfl_xor(mx, 1));
                    mx = fmaxf(mx, __shfl_xor(mx, 2));
                    mx = fmaxf(mx, __shfl_xor(mx, 4));
                    mx = fmaxf(mx, __shfl_xor(mx, 8));
                    float e0 = __expf(v0 - mx), e1 = __expf(v1 - mx);
                    float sm = e0 + e1;
                    sm += __shfl_xor(sm, 1);
                    sm += __shfl_xor(sm, 2);
                    sm += __shfl_xor(sm, 4);
                    sm += __shfl_xor(sm, 8);
                    float inv = 1.0f / sm;
                    int row = rt * 16 + ((lane >> 4) << 2) + i;
                    short h, lo;
                    split2(e0 * inv, h, lo);
                    Qh[row * PH + (lane & 15)] = h;
                    Qh[HL + row * PH + (lane & 15)] = lo;
                    split2(e1 * inv, h, lo);
                    Qh[row * PH + 16 + (lane & 15)] = h;
                    Qh[HL + row * PH + 16 + (lane & 15)] = lo;
                }

            // O = P @ V  (P from QP tile, V from registers)
            f32x4 oA[2][2] = {};
            {
                short8 ph[2], pl[2];
#pragma unroll
                for (int rt = 0; rt < 2; ++rt) {
                    int byte = (rt * 16 + (lane & 15)) * (PH * 2) + ((lane >> 4) << 4);
                    ph[rt] = *(const short8*)((const char*)Qh + byte);
                    pl[rt] = *(const short8*)((const char*)Qh + HL * 2 + byte);
                }
#pragma unroll
                for (int ct = 0; ct < 2; ++ct)
#pragma unroll
                    for (int rt = 0; rt < 2; ++rt) {
                        oA[rt][ct] = MFMA(ph[rt], vbh[ct], oA[rt][ct]);
                        oA[rt][ct] = MFMA(pl[rt], vbh[ct], oA[rt][ct]);
                        oA[rt][ct] = MFMA(ph[rt], vbl[ct], oA[rt][ct]);
                    }
            }

            // barrier HERE: all waves' QKV reads of Ab complete before O overwrites it
            __syncthreads();

            // O -> Ab (hi/lo swizzled); head w owns cols [32w,32w+32)
#pragma unroll
            for (int rt = 0; rt < 2; ++rt)
#pragma unroll
                for (int ct = 0; ct < 2; ++ct)
#pragma unroll
                    for (int i = 0; i < 4; ++i) {
                        int row  = rt * 16 + ((lane >> 4) << 2) + i;
                        int colg = w * 32 + ct * 16 + (lane & 15);
                        int byte = (row * 256 + colg * 2) ^ ((row & 7) << 4);
                        short h, lo;
                        split2(oA[rt][ct][i], h, lo);
                        *(short*)((char*)AbH + byte) = h;
                        *(short*)((char*)AbL + byte) = lo;
                    }
        }
        __syncthreads();

        // x += O @ Wo
        {
            f32x4 ac[2][2] = {};
            mfma_gemm3<4>(AbH, AbL, WL + 3 * 16384 + w * 4096, ac, lane);
#pragma unroll
            for (int c = 0; c < 2; ++c) {
                int colg = w * 32 + c * 16 + (lane & 15);
#pragma unroll
                for (int rt = 0; rt < 2; ++rt)
#pragma unroll
                    for (int i = 0; i < 4; ++i) {
                        int row = rt * 16 + ((lane >> 4) << 2) + i;
                        X[row * PXF + colg] += ac[rt][c][i];
                    }
            }
        }
        __syncthreads();

        // LN2 -> Ab
        ln_to_Ab(X, ln2_s + l * DIM, ln2_b + l * DIM, AbH, AbL, t);
        __syncthreads();

        // FFN: double-buffered Fb, 5 barriers. Regions pair W2(ck) with W1(ck+1)
        // on DISJOINT buffers; each buffer's cross-wave write->read is barrier-separated.
#define FFN_W1(c4, FH, FL) do { \
    f32x4 f1[2][2] = {}; \
    mfma_gemm3<4>(AbH, AbL, WL + (4 + (c4)) * 16384 + w * 4096, f1, lane); \
    _Pragma("unroll") \
    for (int c = 0; c < 2; ++c) { \
        int colg = w * 32 + c * 16 + (lane & 15); \
        float bv = b1[l * DFF + (c4) * 128 + colg]; \
        _Pragma("unroll") \
        for (int rt = 0; rt < 2; ++rt) \
            _Pragma("unroll") \
            for (int i = 0; i < 4; ++i) { \
                int row  = rt * 16 + ((lane >> 4) << 2) + i; \
                float v  = fmaxf(f1[rt][c][i] + bv, 0.0f); \
                int byte = (row * 256 + colg * 2) ^ ((row & 7) << 4); \
                short h, lo; \
                split2(v, h, lo); \
                *(short*)((char*)(FH) + byte) = h; \
                *(short*)((char*)(FL) + byte) = lo; \
            } \
    } \
} while (0)

#define FFN_W2(c4, FH, FL) do { \
    f32x4 f2a[2][2] = {}; \
    mfma_gemm3<4>((FH), (FL), WL + (8 + (c4)) * 16384 + w * 4096, f2a, lane); \
    _Pragma("unroll") \
    for (int c = 0; c < 2; ++c) { \
        int colg = w * 32 + c * 16 + (lane & 15); \
        float bv = ((c4) == 0) ? b2[l * DIM + colg] : 0.0f; \
        _Pragma("unroll") \
        for (int rt = 0; rt < 2; ++rt) \
            _Pragma("unroll") \
            for (int i = 0; i < 4; ++i) { \
                int row = rt * 16 + ((lane >> 4) << 2) + i; \
                X[row * PXF + colg] += f2a[rt][c][i] + bv; \
            } \
    } \
} while (0)

        FFN_W1(0, Fb0H, Fb0L);
        __syncthreads();
        FFN_W2(0, Fb0H, Fb0L);
        FFN_W1(1, Fb1H, Fb1L);
        __syncthreads();
        FFN_W2(1, Fb1H, Fb1L);
        FFN_W1(2, Fb0H, Fb0L);
        __syncthreads();
        FFN_W2(2, Fb0H, Fb0L);
        FFN_W1(3, Fb1H, Fb1L);
        __syncthreads();
        FFN_W2(3, Fb1H, Fb1L);
        __syncthreads();
#undef FFN_W1
#undef FFN_W2
    }

    // ---- pooling logits ----
    {
        const int s = t >> 3, p = t & 7;
        float acc = 0.f;
        const float* row = X + s * PXF + p * 16;
        const float* wp = w_pool + p * 16;
#pragma unroll
        for (int j = 0; j < 16; ++j) acc = fmaf(row[j], wp[j], acc);
#pragma unroll
        for (int off = 1; off < 8; off <<= 1) acc += __shfl_xor(acc, off);
        if (p == 0) LG[s] = acc;
    }
    __syncthreads();
    if (t < DIM) {
        float m = -1e30f;
        for (int s = 0; s < NSEG; ++s) m = fmaxf(m, LG[s]);
        float ssum = 0.f;
        for (int s = 0; s < NSEG; ++s) ssum += __expf(LG[s] - m);
        float inv = 1.0f / ssum;
        float acc = 0.f;
        for (int s = 0; s < NSEG; ++s) acc = fmaf(__expf(LG[s] - m), X[s * PXF + t], acc);
        POOL[t] = acc * inv;
    }
    {
        const int s = t >> 3, p = t & 7;
        float c = 0.f, v = 0.f;
        const float* row = X + s * PXF + p * 16;
#pragma unroll
        for (int j = 0; j < 16; ++j) {
            float x = row[j];
            c = fmaf(x, W_dc[p * 16 + j], c);
            v = fmaf(x, W_dv[p * 16 + j], v);
        }
#pragma unroll
        for (int off = 1; off < 8; off <<= 1) { c += __shfl_xor(c, off); v += __shfl_xor(v, off); }
        if (p == 0) {
            SCC[s] = c + b_dc[0];
            SCV[s] = fminf(fmaxf(v + b_dv[0], 0.0f), 1.0f);
        }
    }
    __syncthreads();
    if (t < 64) {
        float v = POOL[t] * W_hit[t] + POOL[t + 64] * W_hit[t + 64];
#pragma unroll
        for (int off = 1; off < 64; off <<= 1) v += __shfl_xor(v, off);
        if (t == 0) {
            float hv = v + b_hit[0];
            out[ray] = (n_left == 0) ? -100.0f : hv;
        }
    }
    if (t == 255) {
        float best = -1e30f; int am = 0;
        for (int s = 0; s < NSEG; ++s) {
            if (s < n_left) {
                float cv = SCC[s];
                if (cv > best) { best = cv; am = s; }
            }
        }
        out[NRAYS + ray] = SCV[am] + (float)am * SEGL + t1;
    }
}

extern "C" void kernel_launch(void* const* d_in, const int* in_sizes, int n_in,
                              void* d_out, int out_size, void* d_ws, size_t ws_size,
                              hipStream_t stream) {
    (void)in_sizes; (void)n_in; (void)ws_size; (void)out_size;
    const float* points = (const float*)d_in[0];
    const float* W_up   = (const float*)d_in[1];
    const float* b_up   = (const float*)d_in[2];
    const float* ln1_s  = (const float*)d_in[3];
    const float* ln1_b  = (const float*)d_in[4];
    const float* Wq     = (const float*)d_in[5];
    const float* Wk     = (const float*)d_in[6];
    const float* Wv     = (const float*)d_in[7];
    const float* Wo     = (const float*)d_in[8];
    const float* ln2_s  = (const float*)d_in[9];
    const float* ln2_b  = (const float*)d_in[10];
    const float* W1     = (const float*)d_in[11];
    const float* b1     = (const float*)d_in[12];
    const float* W2     = (const float*)d_in[13];
    const float* b2     = (const float*)d_in[14];
    const float* w_pool = (const float*)d_in[15];
    const float* W_hit  = (const float*)d_in[16];
    const float* b_hit  = (const float*)d_in[17];
    const float* W_dc   = (const float*)d_in[18];
    const float* b_dc   = (const float*)d_in[19];
    const float* W_dv   = (const float*)d_in[20];
    const float* b_dv   = (const float*)d_in[21];
    short* Wf = (short*)d_ws;
    float* out = (float*)d_out;

    hipLaunchKernelGGL(prep_weights, dim3(1584), dim3(256), 0, stream,
                       W_up, Wq, Wk, Wv, Wo, W1, W2, Wf);
    hipLaunchKernelGGL(ray_tf_kernel, dim3(NRAYS / 2), dim3(512), 0, stream,
                       points, b_up, ln1_s, ln1_b, ln2_s, ln2_b, b1, b2, w_pool,
                       W_hit, b_hit, W_dc, b_dc, W_dv, b_dv, Wf, out);
}